// Round 7
// baseline (357.608 us; speedup 1.0000x reference)
//
#include <hip/hip_runtime.h>

// AttentionFusion: fused = sigmoid(x1.w - x2.w)*x1 + (1-sig)*x2, per row.
// N=16384 rows, D=2048 cols, fp32.
//
// v7: two-pass, with the dot pass rebuilt in the fuse pass's image.
// v6 isolated the pathology: dot (block-per-row, 6 loads/thread, then
// drain -> shuffle -> LDS -> barrier tail) ran at 2.7 TB/s read while the
// barrier-free streaming fuse pass hit ~12 TB/s effective. Fix the dot:
//   - wave-per-row: 64 lanes own a full row, 8 unrolled iters x (a,b,w)
//     f32x4 loads = 24 independent loads (384 B/lane) hoistable into one
//     deep burst. No LDS, no __syncthreads, nothing after the loads but a
//     register butterfly. Loads die into the accumulator, so the register
//     allocator has no cross-barrier live set to rematerialize (v2b's
//     failure mode doesn't apply: there is no fuse phase here).
//   - lane 0 computes sigmoid and writes alpha[row][2] (8 B).
// Pass 2 (fuse) unchanged: grid-stride elementwise, alpha wave-uniform,
// NT stores keep x1/x2 L3-resident (confirmed by v6: fuse ~33 us).

#define NROWS 16384
#define DCOLS 2048
#define NF4 ((size_t)NROWS * (DCOLS / 4))   // 8,388,608 float4 elements

typedef float f32x4 __attribute__((ext_vector_type(4)));
typedef float f32x2 __attribute__((ext_vector_type(2)));

// ---------------------------------------------------------------- pass 1
// Wave-per-row dot: 4 rows per 256-thread block, 4096 blocks.
__global__ __launch_bounds__(256) void dot_kernel(
    const float* __restrict__ x1,
    const float* __restrict__ x2,
    const float* __restrict__ w,
    float* __restrict__ alpha)
{
    const int lane = threadIdx.x & 63;
    const size_t row = (size_t)(blockIdx.x << 2) + (threadIdx.x >> 6);

    const f32x4* __restrict__ x1v = (const f32x4*)(x1 + row * DCOLS);
    const f32x4* __restrict__ x2v = (const f32x4*)(x2 + row * DCOLS);
    const f32x4* __restrict__ wv  = (const f32x4*)w;

    // 512 f32x4 per row, 64 lanes -> 8 per lane, stride-64 units
    // (each wave instruction covers a contiguous 1 KiB segment).
    float p = 0.0f;
    #pragma unroll
    for (int i = 0; i < 8; ++i) {
        const f32x4 a  = x1v[lane + (i << 6)];
        const f32x4 b  = x2v[lane + (i << 6)];
        const f32x4 ww = wv[lane + (i << 6)];   // 8 KiB total, L1/L2-hot
        p = fmaf(a.x - b.x, ww.x, p);
        p = fmaf(a.y - b.y, ww.y, p);
        p = fmaf(a.z - b.z, ww.z, p);
        p = fmaf(a.w - b.w, ww.w, p);
    }

    // Wave-64 reduce; only lane 0's total matters.
    #pragma unroll
    for (int off = 32; off > 0; off >>= 1)
        p += __shfl_down(p, off, 64);

    if (lane == 0) {
        const float g = 1.0f / (1.0f + expf(-p));   // alpha1 = sigmoid(s1-s2)
        f32x2 al;
        al.x = g;
        al.y = 1.0f - g;
        *(f32x2*)(alpha + row * 2) = al;
    }
}

// ---------------------------------------------------------------- pass 2
// Pure elementwise stream. 2048 blocks x 256 thr, 16 f32x4 per thread.
// Row index = i >> 9 is wave-uniform (512 f32x4 per row, 64 | 512).
__global__ __launch_bounds__(256) void fuse_kernel(
    const float* __restrict__ x1,
    const float* __restrict__ x2,
    const float* __restrict__ alpha,
    float* __restrict__ fused)
{
    const f32x4* __restrict__ av = (const f32x4*)x1;
    const f32x4* __restrict__ bv = (const f32x4*)x2;
    f32x4* __restrict__ ov = (f32x4*)fused;

    const size_t stride = (size_t)gridDim.x * 256;
    size_t i = (size_t)blockIdx.x * 256 + threadIdx.x;

    #pragma unroll 4
    for (; i < NF4; i += stride) {
        const float g = alpha[(i >> 9) << 1];   // alpha1 for this row
        const f32x4 a = av[i];
        const f32x4 b = bv[i];
        f32x4 f;
        f.x = fmaf(g, a.x - b.x, b.x);
        f.y = fmaf(g, a.y - b.y, b.y);
        f.z = fmaf(g, a.z - b.z, b.z);
        f.w = fmaf(g, a.w - b.w, b.w);
        // NT: don't let the 128 MiB output stream evict x1/x2 from L3.
        __builtin_nontemporal_store(f, ov + i);
    }
}

extern "C" void kernel_launch(void* const* d_in, const int* in_sizes, int n_in,
                              void* d_out, int out_size, void* d_ws, size_t ws_size,
                              hipStream_t stream)
{
    const float* x1 = (const float*)d_in[0];
    const float* x2 = (const float*)d_in[1];
    const float* w  = (const float*)d_in[2];

    float* fused = (float*)d_out;                       // [N, D]
    float* alpha = fused + (size_t)NROWS * DCOLS;       // [N, 2]

    dot_kernel<<<NROWS / 4, 256, 0, stream>>>(x1, x2, w, alpha);
    fuse_kernel<<<2048, 256, 0, stream>>>(x1, x2, alpha, fused);
}

// Round 8
// 356.251 us; speedup vs baseline: 1.0038x; 1.0038x over previous
//
#include <hip/hip_runtime.h>

// AttentionFusion: fused = sigmoid(x1.w - x2.w)*x1 + (1-sig)*x2, per row.
// N=16384 rows, D=2048 cols, fp32.
//
// v8: de-paired three-pass.
// Seven structural variants all read x1[i] and x2[i] as a PAIR — addresses
// exactly 2^27 B apart (each array is exactly 128 MiB) — and all pinned at
// ~2.6 TB/s read with FETCH == exactly one array (50% L3 miss). Theory:
// x1[i]/x2[i] alias to the same L3 set / channel slice; the paired working
// set (256 MiB == L3 capacity) thrashes, invariant to kernel structure.
// Fix: never co-stream the pair.
//   k1: s1[row] = x1[row].w      (single-array stream, 128 MiB = L3/2)
//   k2: s2 = x2[row].w; alpha[row] = sigmoid(s1-s2)   (single-array stream)
//   k3: fuse (unchanged from v6/v7: grid-stride, NT stores, ~33 us).
// k1's counters double as a clean single-stream read microbench: if it
// still runs at ~1.3 TB/s HBM, the pairing theory is dead and v1 was
// already at the structural ceiling.

#define NROWS 16384
#define DCOLS 2048
#define NF4 ((size_t)NROWS * (DCOLS / 4))   // 8,388,608 float4 elements

typedef float f32x4 __attribute__((ext_vector_type(4)));
typedef float f32x2 __attribute__((ext_vector_type(2)));

// ---------------------------------------------------------------- pass 1
// s[row] = dot(x[row], w). 2 rows per wave (16 KiB contiguous per wave),
// 2048 blocks x 4 waves x 2 rows = 16384 rows.
__global__ __launch_bounds__(256) void dot_x1_kernel(
    const float* __restrict__ x,
    const float* __restrict__ w,
    float* __restrict__ s)
{
    const int lane = threadIdx.x & 63;
    const size_t r0 = ((size_t)blockIdx.x * 4 + (threadIdx.x >> 6)) * 2;

    const f32x4* __restrict__ xv = (const f32x4*)(x + r0 * DCOLS);
    const f32x4* __restrict__ wv = (const f32x4*)w;

    float pa = 0.0f, pb = 0.0f;
    #pragma unroll
    for (int i = 0; i < 8; ++i) {
        const f32x4 xa = xv[lane + (i << 6)];        // row r0
        const f32x4 xb = xv[lane + ((i + 8) << 6)];  // row r0+1 (contiguous)
        const f32x4 ww = wv[lane + (i << 6)];        // 8 KiB, L1-hot
        pa = fmaf(xa.x, ww.x, pa); pa = fmaf(xa.y, ww.y, pa);
        pa = fmaf(xa.z, ww.z, pa); pa = fmaf(xa.w, ww.w, pa);
        pb = fmaf(xb.x, ww.x, pb); pb = fmaf(xb.y, ww.y, pb);
        pb = fmaf(xb.z, ww.z, pb); pb = fmaf(xb.w, ww.w, pb);
    }

    #pragma unroll
    for (int off = 32; off > 0; off >>= 1) {
        pa += __shfl_down(pa, off, 64);
        pb += __shfl_down(pb, off, 64);
    }

    if (lane == 0) {
        f32x2 sv; sv.x = pa; sv.y = pb;
        *(f32x2*)(s + r0) = sv;
    }
}

// ---------------------------------------------------------------- pass 2
// s2 = dot(x2[row], w); alpha[row] = {sigmoid(s1-s2), 1-sigmoid(s1-s2)}.
__global__ __launch_bounds__(256) void dot_x2_kernel(
    const float* __restrict__ x,
    const float* __restrict__ w,
    const float* __restrict__ s1,
    float* __restrict__ alpha)
{
    const int lane = threadIdx.x & 63;
    const size_t r0 = ((size_t)blockIdx.x * 4 + (threadIdx.x >> 6)) * 2;

    const f32x4* __restrict__ xv = (const f32x4*)(x + r0 * DCOLS);
    const f32x4* __restrict__ wv = (const f32x4*)w;

    float pa = 0.0f, pb = 0.0f;
    #pragma unroll
    for (int i = 0; i < 8; ++i) {
        const f32x4 xa = xv[lane + (i << 6)];
        const f32x4 xb = xv[lane + ((i + 8) << 6)];
        const f32x4 ww = wv[lane + (i << 6)];
        pa = fmaf(xa.x, ww.x, pa); pa = fmaf(xa.y, ww.y, pa);
        pa = fmaf(xa.z, ww.z, pa); pa = fmaf(xa.w, ww.w, pa);
        pb = fmaf(xb.x, ww.x, pb); pb = fmaf(xb.y, ww.y, pb);
        pb = fmaf(xb.z, ww.z, pb); pb = fmaf(xb.w, ww.w, pb);
    }

    #pragma unroll
    for (int off = 32; off > 0; off >>= 1) {
        pa += __shfl_down(pa, off, 64);
        pb += __shfl_down(pb, off, 64);
    }

    if (lane == 0) {
        const f32x2 s1v = *(const f32x2*)(s1 + r0);  // L2-hot, 8 B
        const float ga = 1.0f / (1.0f + expf(-(s1v.x - pa)));
        const float gb = 1.0f / (1.0f + expf(-(s1v.y - pb)));
        f32x4 al; al.x = ga; al.y = 1.0f - ga; al.z = gb; al.w = 1.0f - gb;
        *(f32x4*)(alpha + r0 * 2) = al;
    }
}

// ---------------------------------------------------------------- pass 3
// Pure elementwise stream (proven ~33 us in v6/v7). Row index i>>9 is
// wave-uniform (512 f32x4 per row, 64 | 512).
__global__ __launch_bounds__(256) void fuse_kernel(
    const float* __restrict__ x1,
    const float* __restrict__ x2,
    const float* __restrict__ alpha,
    float* __restrict__ fused)
{
    const f32x4* __restrict__ av = (const f32x4*)x1;
    const f32x4* __restrict__ bv = (const f32x4*)x2;
    f32x4* __restrict__ ov = (f32x4*)fused;

    const size_t stride = (size_t)gridDim.x * 256;
    size_t i = (size_t)blockIdx.x * 256 + threadIdx.x;

    #pragma unroll 4
    for (; i < NF4; i += stride) {
        const float g = alpha[(i >> 9) << 1];   // alpha1 for this row
        const f32x4 a = av[i];
        const f32x4 b = bv[i];
        f32x4 f;
        f.x = fmaf(g, a.x - b.x, b.x);
        f.y = fmaf(g, a.y - b.y, b.y);
        f.z = fmaf(g, a.z - b.z, b.z);
        f.w = fmaf(g, a.w - b.w, b.w);
        // NT: don't let the 128 MiB output stream evict x1/x2 from caches.
        __builtin_nontemporal_store(f, ov + i);
    }
}

extern "C" void kernel_launch(void* const* d_in, const int* in_sizes, int n_in,
                              void* d_out, int out_size, void* d_ws, size_t ws_size,
                              hipStream_t stream)
{
    const float* x1 = (const float*)d_in[0];
    const float* x2 = (const float*)d_in[1];
    const float* w  = (const float*)d_in[2];

    float* fused = (float*)d_out;                       // [N, D]
    float* alpha = fused + (size_t)NROWS * DCOLS;       // [N, 2]
    float* s1    = (float*)d_ws;                        // [N] workspace

    dot_x1_kernel<<<2048, 256, 0, stream>>>(x1, w, s1);
    dot_x2_kernel<<<2048, 256, 0, stream>>>(x2, w, s1, alpha);
    fuse_kernel<<<2048, 256, 0, stream>>>(x1, x2, alpha, fused);
}